// Round 9
// baseline (1678.919 us; speedup 1.0000x reference)
//
#include <hip/hip_runtime.h>
#include <math.h>

// PURE F32 literal pipeline, strict no-FMA (__fmul_rn/__fadd_rn), f32 storage
// of every intermediate, index-order sums. Rationale (r2-r8 evidence): the np
// reference is f32-grade; the two discrepant pool sites are decided by f32
// roundings SHARED across implementations -- f32 stores + f32-rounded
// products (no FMA). My earlier f32 attempt (r2/r3) used FMA and flipped
// site B; exact-f64 (r4-r8) flips site A. This version replicates the shared
// f32 error components exactly: products rounded per-term, sums f32
// sequential, sqrt/div correctly-rounded f32 (identical in all IEEE impls),
// pow = f64-computed, f32-rounded (consensus surrogate), qv/expo in f32.

#define C_CH   128
#define NCHK   8

// ---- f32 workspace layout (float offsets) ----
#define F_WN1    0         // [80][75]
#define F_WN2D   6000      // [80][9]
#define F_WN2PT  6720      // [c=80][o=40]
#define F_WN3    9920      // [40][360]
#define F_EXPO1  24320
#define F_EXPO2D 24400
#define F_EXPO2P 24480
#define F_EXPO3  24520
#define F_QV     24560     // 4
#define F_A1     24576     // chunk conv1 f-out: 128*80*28*28 = 8028160
#define F_T1C    8052736   // chunk pooled:      128*80*14*14 = 2007040
#define F_A2D    10059776  // chunk depthwise:   128*80*12*12 = 1474560
#define F_A2P    11534336  // chunk pointwise:   128*40*12*12 = 737280
#define F_T2C    12271616  // chunk pooled:      128*40*6*6   = 184320
#define F_A3     12455936  // chunk conv3 f-out: 128*40*4*4   = 81920
#define F_VAL    12537856  // chunk final:       128*40       = 5120
#define F_END    12542976  // floats = 50.2 MB

// f32 sharpened-cosine pow: operand chain in f32 (matches refs' stored-f32
// dataflow); the transcendental itself evaluated in f64 and rounded once.
__device__ __forceinline__ float scs_pow_f(float y, float e) {
  const float a  = __fadd_rn(fabsf(y), 1e-12f);
  const float pw = (float)pow((double)a, (double)e);
  return (y > 0.f) ? pw : ((y < 0.f) ? -pw : 0.f);
}

// maxabs select on f32 values, reference rule: where(pos >= -neg, pos, neg)
__device__ __forceinline__ float pool_sel(float mx, float mn) {
  return (mx >= -mn) ? mx : mn;
}

// ---------------- weight prep ----------------
// Norm sums in f64 (consensus; jax/np orders differ here anyway and no
// decision sits on them), then all subsequent ops on the f32 grid like refs.
__global__ __launch_bounds__(256) void k_prep(
    const float* __restrict__ w1,  const float* __restrict__ p1,  const float* __restrict__ q1,
    const float* __restrict__ w2d, const float* __restrict__ p2d, const float* __restrict__ q2d,
    const float* __restrict__ w2p, const float* __restrict__ p2p, const float* __restrict__ q2p,
    const float* __restrict__ w3,  const float* __restrict__ p3,  const float* __restrict__ q3,
    float* __restrict__ ws)
{
  const int tid = threadIdx.x;
  const float t1q = __fdiv_rn(q1[0],  100.0f);
  const float t2q = __fdiv_rn(q2d[0], 100.0f);
  const float t3q = __fdiv_rn(q2p[0], 100.0f);
  const float t4q = __fdiv_rn(q3[0],  100.0f);
  const float qv1  = __fmul_rn(t1q, t1q);
  const float qv2d = __fmul_rn(t2q, t2q);
  const float qv2p = __fmul_rn(t3q, t3q);
  const float qv3  = __fmul_rn(t4q, t4q);
  if (tid == 0) {
    ws[F_QV+0] = qv1; ws[F_QV+1] = qv2d; ws[F_QV+2] = qv2p; ws[F_QV+3] = qv3;
  }
  if (tid < 80) {                       // layer 1
    const int o = tid;
    double s = 0.0;
    for (int k = 0; k < 75; ++k) { double v = (double)w1[o*75+k]; s += v*v; }
    const float sum32 = (float)s;
    const float norm = __fadd_rn(__fsqrt_rn(__fadd_rn(sum32, 1e-12f)), qv1);
    for (int k = 0; k < 75; ++k) ws[F_WN1 + o*75 + k] = __fdiv_rn(w1[o*75+k], norm);
    const float pp = __fdiv_rn(p1[o], 10.0f);
    ws[F_EXPO1 + o] = __fmul_rn(pp, pp);
  }
  if (tid < 80) {                       // layer 2 depthwise
    const int o = tid;
    double s = 0.0;
    for (int k = 0; k < 9; ++k) { double v = (double)w2d[o*9+k]; s += v*v; }
    const float sum32 = (float)s;
    const float norm = __fadd_rn(__fsqrt_rn(__fadd_rn(sum32, 1e-12f)), qv2d);
    for (int k = 0; k < 9; ++k) ws[F_WN2D + o*9 + k] = __fdiv_rn(w2d[o*9+k], norm);
    const float pp = __fdiv_rn(p2d[o], 10.0f);
    ws[F_EXPO2D + o] = __fmul_rn(pp, pp);
  }
  if (tid < 40) {                       // layer 2 pointwise, store [c][o]
    const int o = tid;
    double s = 0.0;
    for (int k = 0; k < 80; ++k) { double v = (double)w2p[o*80+k]; s += v*v; }
    const float sum32 = (float)s;
    const float norm = __fadd_rn(__fsqrt_rn(__fadd_rn(sum32, 1e-12f)), qv2p);
    for (int k = 0; k < 80; ++k) ws[F_WN2PT + k*40 + o] = __fdiv_rn(w2p[o*80+k], norm);
    const float pp = __fdiv_rn(p2p[o], 10.0f);
    ws[F_EXPO2P + o] = __fmul_rn(pp, pp);
  }
  if (tid < 40) {                       // layer 3
    const int o = tid;
    double s = 0.0;
    for (int k = 0; k < 360; ++k) { double v = (double)w3[o*360+k]; s += v*v; }
    const float sum32 = (float)s;
    const float norm = __fadd_rn(__fsqrt_rn(__fadd_rn(sum32, 1e-12f)), qv3);
    for (int k = 0; k < 360; ++k) ws[F_WN3 + o*360 + k] = __fdiv_rn(w3[o*360+k], norm);
    const float pp = __fdiv_rn(p3[o], 10.0f);
    ws[F_EXPO3 + o] = __fmul_rn(pp, pp);
  }
}

// ---- layer 1 scs: out f map (n,o,28,28), f32 no-FMA ----
__global__ __launch_bounds__(256) void k1_scs(
    const float* __restrict__ x, float* __restrict__ ws, int n0)
{
  const int idx = blockIdx.x * 256 + threadIdx.x;
  if (idx >= C_CH*80*784) return;
  const int p  = idx % 784;
  const int o  = (idx / 784) % 80;
  const int n  = idx / (80*784);
  const int py = p / 28, px = p % 28;
  const float* xb = x + (size_t)(n0 + n) * 3072;
  const float* wn = ws + F_WN1 + o*75;
  float num = 0.f, ss = 0.f;
  for (int c = 0; c < 3; ++c)
    for (int i = 0; i < 5; ++i)
      for (int j = 0; j < 5; ++j) {
        const float v = xb[c*1024 + (py+i)*32 + (px+j)];
        num = __fadd_rn(num, __fmul_rn(v, wn[c*25 + i*5 + j]));
        ss  = __fadd_rn(ss,  __fmul_rn(v, v));
      }
  const float xn = __fadd_rn(__fsqrt_rn(__fadd_rn(ss, 1e-12f)), ws[F_QV+0]);
  const float y  = __fdiv_rn(num, xn);
  ws[F_A1 + idx] = scs_pow_f(y, ws[F_EXPO1 + o]);
}

// ---- pool 2x2/2 on (n,o,28,28) -> (n,o,14,14) ----
__global__ __launch_bounds__(256) void k1_pool(float* __restrict__ ws)
{
  const int idx = blockIdx.x * 256 + threadIdx.x;
  if (idx >= C_CH*80*196) return;
  const int cell = idx % 196;
  const int no   = idx / 196;
  const int py = cell / 14, px = cell % 14;
  const float* a = ws + F_A1 + (size_t)no * 784;
  const float f0 = a[(2*py  )*28 + 2*px], f1 = a[(2*py  )*28 + 2*px+1];
  const float f2 = a[(2*py+1)*28 + 2*px], f3 = a[(2*py+1)*28 + 2*px+1];
  const float mx = fmaxf(fmaxf(f0, f1), fmaxf(f2, f3));
  const float mn = fminf(fminf(f0, f1), fminf(f2, f3));
  ws[F_T1C + idx] = pool_sel(mx, mn);
}

// ---- layer 2 depthwise scs: (n,80,14,14) -> (n,80,12,12) ----
__global__ __launch_bounds__(256) void k2_dw(float* __restrict__ ws)
{
  const int idx = blockIdx.x * 256 + threadIdx.x;
  if (idx >= C_CH*80*144) return;
  const int pp = idx % 144;
  const int c  = (idx / 144) % 80;
  const int nc = idx / 144;
  const int y = pp / 12, xx = pp % 12;
  const float* src = ws + F_T1C + (size_t)nc * 196;
  const float* wd  = ws + F_WN2D + c*9;
  float num = 0.f, ss = 0.f;
  for (int i = 0; i < 3; ++i)
    for (int j = 0; j < 3; ++j) {
      const float v = src[(y+i)*14 + xx + j];
      num = __fadd_rn(num, __fmul_rn(v, wd[i*3+j]));
      ss  = __fadd_rn(ss,  __fmul_rn(v, v));
    }
  const float xn = __fadd_rn(__fsqrt_rn(__fadd_rn(ss, 1e-12f)), ws[F_QV+1]);
  const float yv = __fdiv_rn(num, xn);
  ws[F_A2D + idx] = scs_pow_f(yv, ws[F_EXPO2D + c]);
}

// ---- layer 2 pointwise scs: (n,80,12,12) -> (n,40,12,12) ----
__global__ __launch_bounds__(256) void k2_pw(float* __restrict__ ws)
{
  const int idx = blockIdx.x * 256 + threadIdx.x;
  if (idx >= C_CH*40*144) return;
  const int pp = idx % 144;
  const int o  = (idx / 144) % 40;
  const int n  = idx / (40*144);
  const float* a = ws + F_A2D + (size_t)n * 80 * 144 + pp;
  const float* wp = ws + F_WN2PT;          // [c][o]
  float num = 0.f, ss = 0.f;
  for (int c = 0; c < 80; ++c) {
    const float v = a[(size_t)c * 144];
    num = __fadd_rn(num, __fmul_rn(v, wp[c*40 + o]));
    ss  = __fadd_rn(ss,  __fmul_rn(v, v));
  }
  const float xn = __fadd_rn(__fsqrt_rn(__fadd_rn(ss, 1e-12f)), ws[F_QV+2]);
  const float yv = __fdiv_rn(num, xn);
  ws[F_A2P + idx] = scs_pow_f(yv, ws[F_EXPO2P + o]);
}

// ---- pool 2x2/2 on (n,40,12,12) -> (n,40,6,6) ----
__global__ __launch_bounds__(256) void k2_pool(float* __restrict__ ws)
{
  const int idx = blockIdx.x * 256 + threadIdx.x;
  if (idx >= C_CH*40*36) return;
  const int cell = idx % 36;
  const int no   = idx / 36;
  const int qy = cell / 6, qx = cell % 6;
  const float* a = ws + F_A2P + (size_t)no * 144;
  const float f0 = a[(2*qy  )*12 + 2*qx], f1 = a[(2*qy  )*12 + 2*qx+1];
  const float f2 = a[(2*qy+1)*12 + 2*qx], f3 = a[(2*qy+1)*12 + 2*qx+1];
  const float mx = fmaxf(fmaxf(f0, f1), fmaxf(f2, f3));
  const float mn = fminf(fminf(f0, f1), fminf(f2, f3));
  ws[F_T2C + idx] = pool_sel(mx, mn);
}

// ---- layer 3 scs: (n,40,6,6) -> (n,40,4,4) ----
__global__ __launch_bounds__(256) void k3_scs(float* __restrict__ ws)
{
  const int idx = blockIdx.x * 256 + threadIdx.x;
  if (idx >= C_CH*40*16) return;
  const int pos = idx % 16;
  const int o   = (idx / 16) % 40;
  const int n   = idx / (40*16);
  const int y = pos / 4, xx = pos % 4;
  const float* t2 = ws + F_T2C + (size_t)n * 40 * 36;
  const float* wn = ws + F_WN3 + o*360;
  float num = 0.f, ss = 0.f;
  for (int c = 0; c < 40; ++c)
    for (int i = 0; i < 3; ++i)
      for (int j = 0; j < 3; ++j) {
        const float v = t2[c*36 + (y+i)*6 + xx + j];
        num = __fadd_rn(num, __fmul_rn(v, wn[c*9 + i*3 + j]));
        ss  = __fadd_rn(ss,  __fmul_rn(v, v));
      }
  const float xn = __fadd_rn(__fsqrt_rn(__fadd_rn(ss, 1e-12f)), ws[F_QV+3]);
  const float yv = __fdiv_rn(num, xn);
  ws[F_A3 + idx] = scs_pow_f(yv, ws[F_EXPO3 + o]);
}

// ---- pool 4x4/4 on (n,40,4,4) -> (n,40) ----
__global__ __launch_bounds__(256) void k3_pool(float* __restrict__ ws)
{
  const int idx = blockIdx.x * 256 + threadIdx.x;
  if (idx >= C_CH*40) return;
  const float* a = ws + F_A3 + (size_t)idx * 16;
  float mx = a[0], mn = a[0];
  for (int k = 1; k < 16; ++k) {
    mx = fmaxf(mx, a[k]);
    mn = fminf(mn, a[k]);
  }
  ws[F_VAL + idx] = pool_sel(mx, mn);
}

// ---- head: (n,40) @ wo.T + bo -> out (n,10), f32 no-FMA ----
__global__ __launch_bounds__(256) void k_head(
    const float* __restrict__ ws, const float* __restrict__ wo,
    const float* __restrict__ bo, float* __restrict__ out, int n0)
{
  const int idx = blockIdx.x * 256 + threadIdx.x;
  if (idx >= C_CH*10) return;
  const int k = idx % 10;
  const int n = idx / 10;
  const float* v = ws + F_VAL + (size_t)n * 40;
  float s = 0.f;
  for (int c = 0; c < 40; ++c) s = __fadd_rn(s, __fmul_rn(v[c], wo[k*40 + c]));
  s = __fadd_rn(s, bo[k]);
  out[(size_t)(n0 + n) * 10 + k] = s;
}

extern "C" void kernel_launch(void* const* d_in, const int* in_sizes, int n_in,
                              void* d_out, int out_size, void* d_ws, size_t ws_size,
                              hipStream_t stream) {
  (void)in_sizes; (void)n_in; (void)out_size; (void)ws_size;
  const float* x   = (const float*)d_in[0];
  const float* w1  = (const float*)d_in[1];
  const float* p1  = (const float*)d_in[2];
  const float* q1  = (const float*)d_in[3];
  const float* w2d = (const float*)d_in[4];
  const float* p2d = (const float*)d_in[5];
  const float* q2d = (const float*)d_in[6];
  const float* w2p = (const float*)d_in[7];
  const float* p2p = (const float*)d_in[8];
  const float* q2p = (const float*)d_in[9];
  const float* w3  = (const float*)d_in[10];
  const float* p3  = (const float*)d_in[11];
  const float* q3  = (const float*)d_in[12];
  const float* wo  = (const float*)d_in[13];
  const float* bo  = (const float*)d_in[14];
  float* ws  = (float*)d_ws;
  float* out = (float*)d_out;

  hipLaunchKernelGGL(k_prep, dim3(1), dim3(256), 0, stream,
                     w1, p1, q1, w2d, p2d, q2d, w2p, p2p, q2p, w3, p3, q3, ws);

  const int g1  = (C_CH*80*784 + 255) / 256;
  const int g1p = (C_CH*80*196 + 255) / 256;
  const int g2d = (C_CH*80*144 + 255) / 256;
  const int g2p = (C_CH*40*144 + 255) / 256;
  const int g2q = (C_CH*40*36  + 255) / 256;
  const int g3  = (C_CH*40*16  + 255) / 256;
  const int g3p = (C_CH*40     + 255) / 256;
  const int gh  = (C_CH*10     + 255) / 256;

  for (int c = 0; c < NCHK; ++c) {
    const int n0 = c * C_CH;
    hipLaunchKernelGGL(k1_scs,  dim3(g1),  dim3(256), 0, stream, x, ws, n0);
    hipLaunchKernelGGL(k1_pool, dim3(g1p), dim3(256), 0, stream, ws);
    hipLaunchKernelGGL(k2_dw,   dim3(g2d), dim3(256), 0, stream, ws);
    hipLaunchKernelGGL(k2_pw,   dim3(g2p), dim3(256), 0, stream, ws);
    hipLaunchKernelGGL(k2_pool, dim3(g2q), dim3(256), 0, stream, ws);
    hipLaunchKernelGGL(k3_scs,  dim3(g3),  dim3(256), 0, stream, ws);
    hipLaunchKernelGGL(k3_pool, dim3(g3p), dim3(256), 0, stream, ws);
    hipLaunchKernelGGL(k_head,  dim3(gh),  dim3(256), 0, stream, ws, wo, bo, out, n0);
  }
}

// Round 12
// 851.001 us; speedup vs baseline: 1.9729x; 1.9729x over previous
//
#include <hip/hip_runtime.h>
#include <math.h>

// F32 no-FMA literal-semantics pipeline (r9 bit contract).
// ROUND-12 BISECT: fast-pow path DELETED — every pow is the r9-proven
// (float)pow((double)a,(double)e). Structure keeps the provably-bit-exact
// transformations from r10/r11:
//  - shared patch norms (identical __fadd_rn/__fmul_rn chain order)
//  - pool fused into scs kernels, ILP-4 window accumulators (per-acc
//    canonical (c,i,j) chains)
//  - y-domain pooling: round(pow(.)) is monotone odd => fmax/fmin commute
//    with it bit-exactly; 2 pows per pooled cell (pos/neg candidates),
//    final compare fp >= -fn on f32 f values per the reference rule.
// If this passes with absmax 6.1e-5 -> r10/r11's fast-pow was the bug.
// If this fails at 0.00574 -> the restructure is the bug.

// ---- f32 workspace layout (float offsets) ----
#define F_WN1    0         // [80][75]
#define F_WN2D   6000      // [80][9]
#define F_WN2PT  6720      // [c=80][o=40]
#define F_WN3    9920      // [40][360]
#define F_EXPO1  24320
#define F_EXPO2D 24400
#define F_EXPO2P 24480
#define F_EXPO3  24520
#define F_QV     24560     // 4
#define F_XN1    24576     // [1024][784]
#define F_T1     827392    // [1024][80][196] pooled layer1 (f values)
#define F_A2D    16883712  // [1024][80][144] depthwise f values
#define F_XN2    28680192  // [1024][144]
#define F_T2     28827648  // [1024][40][36] pooled layer2 (f values)
#define F_XN3    30302208  // [1024][16]
#define F_A3     30318592  // [1024][40][16] layer3 y values (pre-pow)
#define F_VAL    30973952  // [1024][40] pooled layer3 (f values)
#define F_END    31014912  // floats = 124.06 MB

// r9-proven exact pow. Do NOT approximate: a 1-ulp deviation anywhere can
// flip a sub-ulp pool margin (r10/r11 lesson).
__device__ __forceinline__ float scs_pow_f(float y, float e) {
  const float a  = __fadd_rn(fabsf(y), 1e-12f);
  const float pw = (float)pow((double)a, (double)e);
  return (y > 0.f) ? pw : ((y < 0.f) ? -pw : 0.f);
}

// ---------------- weight prep (r9-proven, unchanged) ----------------
__global__ __launch_bounds__(256) void k_prep(
    const float* __restrict__ w1,  const float* __restrict__ p1,  const float* __restrict__ q1,
    const float* __restrict__ w2d, const float* __restrict__ p2d, const float* __restrict__ q2d,
    const float* __restrict__ w2p, const float* __restrict__ p2p, const float* __restrict__ q2p,
    const float* __restrict__ w3,  const float* __restrict__ p3,  const float* __restrict__ q3,
    float* __restrict__ ws)
{
  const int tid = threadIdx.x;
  const float t1q = __fdiv_rn(q1[0],  100.0f);
  const float t2q = __fdiv_rn(q2d[0], 100.0f);
  const float t3q = __fdiv_rn(q2p[0], 100.0f);
  const float t4q = __fdiv_rn(q3[0],  100.0f);
  const float qv1  = __fmul_rn(t1q, t1q);
  const float qv2d = __fmul_rn(t2q, t2q);
  const float qv2p = __fmul_rn(t3q, t3q);
  const float qv3  = __fmul_rn(t4q, t4q);
  if (tid == 0) {
    ws[F_QV+0] = qv1; ws[F_QV+1] = qv2d; ws[F_QV+2] = qv2p; ws[F_QV+3] = qv3;
  }
  if (tid < 80) {
    const int o = tid;
    double s = 0.0;
    for (int k = 0; k < 75; ++k) { double v = (double)w1[o*75+k]; s += v*v; }
    const float norm = __fadd_rn(__fsqrt_rn(__fadd_rn((float)s, 1e-12f)), qv1);
    for (int k = 0; k < 75; ++k) ws[F_WN1 + o*75 + k] = __fdiv_rn(w1[o*75+k], norm);
    const float pp = __fdiv_rn(p1[o], 10.0f);
    ws[F_EXPO1 + o] = __fmul_rn(pp, pp);
  }
  if (tid < 80) {
    const int o = tid;
    double s = 0.0;
    for (int k = 0; k < 9; ++k) { double v = (double)w2d[o*9+k]; s += v*v; }
    const float norm = __fadd_rn(__fsqrt_rn(__fadd_rn((float)s, 1e-12f)), qv2d);
    for (int k = 0; k < 9; ++k) ws[F_WN2D + o*9 + k] = __fdiv_rn(w2d[o*9+k], norm);
    const float pp = __fdiv_rn(p2d[o], 10.0f);
    ws[F_EXPO2D + o] = __fmul_rn(pp, pp);
  }
  if (tid < 40) {
    const int o = tid;
    double s = 0.0;
    for (int k = 0; k < 80; ++k) { double v = (double)w2p[o*80+k]; s += v*v; }
    const float norm = __fadd_rn(__fsqrt_rn(__fadd_rn((float)s, 1e-12f)), qv2p);
    for (int k = 0; k < 80; ++k) ws[F_WN2PT + k*40 + o] = __fdiv_rn(w2p[o*80+k], norm);
    const float pp = __fdiv_rn(p2p[o], 10.0f);
    ws[F_EXPO2P + o] = __fmul_rn(pp, pp);
  }
  if (tid < 40) {
    const int o = tid;
    double s = 0.0;
    for (int k = 0; k < 360; ++k) { double v = (double)w3[o*360+k]; s += v*v; }
    const float norm = __fadd_rn(__fsqrt_rn(__fadd_rn((float)s, 1e-12f)), qv3);
    for (int k = 0; k < 360; ++k) ws[F_WN3 + o*360 + k] = __fdiv_rn(w3[o*360+k], norm);
    const float pp = __fdiv_rn(p3[o], 10.0f);
    ws[F_EXPO3 + o] = __fmul_rn(pp, pp);
  }
}

// ---- layer1 patch norms (canonical c,i,j chain) ----
__global__ __launch_bounds__(256) void k1_norm(
    const float* __restrict__ x, float* __restrict__ ws)
{
  const int idx = blockIdx.x * 256 + threadIdx.x;
  if (idx >= 1024*784) return;
  const int p = idx % 784;
  const int n = idx / 784;
  const int py = p / 28, px = p % 28;
  const float* xb = x + (size_t)n * 3072;
  float ss = 0.f;
  for (int c = 0; c < 3; ++c)
    for (int i = 0; i < 5; ++i)
      for (int j = 0; j < 5; ++j) {
        const float v = xb[c*1024 + (py+i)*32 + (px+j)];
        ss = __fadd_rn(ss, __fmul_rn(v, v));
      }
  ws[F_XN1 + idx] = __fadd_rn(__fsqrt_rn(__fadd_rn(ss, 1e-12f)), ws[F_QV+0]);
}

// ---- layer1 scs + pool (y-domain pool, 2 exact pows) ----
__global__ __launch_bounds__(256) void k1_scs_pool(
    const float* __restrict__ x, float* __restrict__ ws)
{
  const int idx = blockIdx.x * 256 + threadIdx.x;
  if (idx >= 1024*80*196) return;
  const int cell = idx % 196;
  const int o    = (idx / 196) % 80;
  const int n    = idx / (80*196);
  const int py = cell / 14, px = cell % 14;
  const int ry = 2*py, rx = 2*px;
  const float* xb = x + (size_t)n * 3072;
  const float* wn = ws + F_WN1 + o*75;
  float num0=0.f, num1=0.f, num2=0.f, num3=0.f;
  for (int c = 0; c < 3; ++c) {
    float xv[6][6];
    #pragma unroll
    for (int i = 0; i < 6; ++i)
      #pragma unroll
      for (int j = 0; j < 6; ++j)
        xv[i][j] = xb[c*1024 + (ry+i)*32 + (rx+j)];
    #pragma unroll
    for (int i = 0; i < 5; ++i)
      #pragma unroll
      for (int j = 0; j < 5; ++j) {
        const float w = wn[c*25 + i*5 + j];
        num0 = __fadd_rn(num0, __fmul_rn(xv[i  ][j  ], w));
        num1 = __fadd_rn(num1, __fmul_rn(xv[i  ][j+1], w));
        num2 = __fadd_rn(num2, __fmul_rn(xv[i+1][j  ], w));
        num3 = __fadd_rn(num3, __fmul_rn(xv[i+1][j+1], w));
      }
  }
  const float* xn = ws + F_XN1 + (size_t)n * 784;
  const float y0 = __fdiv_rn(num0, xn[ ry   *28 + rx  ]);
  const float y1 = __fdiv_rn(num1, xn[ ry   *28 + rx+1]);
  const float y2 = __fdiv_rn(num2, xn[(ry+1)*28 + rx  ]);
  const float y3 = __fdiv_rn(num3, xn[(ry+1)*28 + rx+1]);
  // round(pow(.)) monotone odd => fmax/fmin commute with it bit-exactly
  const float ymax = fmaxf(fmaxf(y0, y1), fmaxf(y2, y3));
  const float ymin = fminf(fminf(y0, y1), fminf(y2, y3));
  const float e  = ws[F_EXPO1 + o];
  const float fp = scs_pow_f(ymax, e);
  const float fn = scs_pow_f(ymin, e);
  ws[F_T1 + idx] = (fp >= -fn) ? fp : fn;
}

// ---- layer2 depthwise (exact pow every output; no pool) ----
__global__ __launch_bounds__(256) void k2_dw(float* __restrict__ ws)
{
  const int idx = blockIdx.x * 256 + threadIdx.x;
  if (idx >= 1024*80*144) return;
  const int pp = idx % 144;
  const int c  = (idx / 144) % 80;
  const int nc = idx / 144;
  const int y = pp / 12, xx = pp % 12;
  const float* src = ws + F_T1 + (size_t)nc * 196;
  const float* wd  = ws + F_WN2D + c*9;
  float num = 0.f, ss = 0.f;
  for (int i = 0; i < 3; ++i)
    for (int j = 0; j < 3; ++j) {
      const float v = src[(y+i)*14 + xx + j];
      num = __fadd_rn(num, __fmul_rn(v, wd[i*3+j]));
      ss  = __fadd_rn(ss,  __fmul_rn(v, v));
    }
  const float xn = __fadd_rn(__fsqrt_rn(__fadd_rn(ss, 1e-12f)), ws[F_QV+1]);
  ws[F_A2D + idx] = scs_pow_f(__fdiv_rn(num, xn), ws[F_EXPO2D + c]);
}

// ---- layer2 pointwise norms (canonical c chain) ----
__global__ __launch_bounds__(256) void k2_norm(float* __restrict__ ws)
{
  const int idx = blockIdx.x * 256 + threadIdx.x;
  if (idx >= 1024*144) return;
  const int pp = idx % 144;
  const int n  = idx / 144;
  const float* a = ws + F_A2D + (size_t)n * 80 * 144 + pp;
  float ss = 0.f;
  for (int c = 0; c < 80; ++c) {
    const float v = a[(size_t)c * 144];
    ss = __fadd_rn(ss, __fmul_rn(v, v));
  }
  ws[F_XN2 + idx] = __fadd_rn(__fsqrt_rn(__fadd_rn(ss, 1e-12f)), ws[F_QV+2]);
}

// ---- layer2 pointwise scs + pool (y-domain pool, 2 exact pows) ----
__global__ __launch_bounds__(256) void k2_pw_pool(float* __restrict__ ws)
{
  const int idx = blockIdx.x * 256 + threadIdx.x;
  if (idx >= 1024*40*36) return;
  const int cell = idx % 36;
  const int o    = (idx / 36) % 40;
  const int n    = idx / (40*36);
  const int qy = cell / 6, qx = cell % 6;
  const int p0 = (2*qy)*12 + 2*qx;
  const float* a  = ws + F_A2D + (size_t)n * 80 * 144;
  const float* wp = ws + F_WN2PT;
  float num0=0.f, num1=0.f, num2=0.f, num3=0.f;
  for (int c = 0; c < 80; ++c) {
    const float w = wp[c*40 + o];
    const float* ac = a + (size_t)c*144 + p0;
    num0 = __fadd_rn(num0, __fmul_rn(ac[0],  w));
    num1 = __fadd_rn(num1, __fmul_rn(ac[1],  w));
    num2 = __fadd_rn(num2, __fmul_rn(ac[12], w));
    num3 = __fadd_rn(num3, __fmul_rn(ac[13], w));
  }
  const float* xn = ws + F_XN2 + (size_t)n * 144 + p0;
  const float y0 = __fdiv_rn(num0, xn[0]);
  const float y1 = __fdiv_rn(num1, xn[1]);
  const float y2 = __fdiv_rn(num2, xn[12]);
  const float y3 = __fdiv_rn(num3, xn[13]);
  const float ymax = fmaxf(fmaxf(y0, y1), fmaxf(y2, y3));
  const float ymin = fminf(fminf(y0, y1), fminf(y2, y3));
  const float e  = ws[F_EXPO2P + o];
  const float fp = scs_pow_f(ymax, e);
  const float fn = scs_pow_f(ymin, e);
  ws[F_T2 + idx] = (fp >= -fn) ? fp : fn;
}

// ---- layer3 norms (canonical c,i,j chain) ----
__global__ __launch_bounds__(256) void k3_norm(float* __restrict__ ws)
{
  const int idx = blockIdx.x * 256 + threadIdx.x;
  if (idx >= 1024*16) return;
  const int pos = idx % 16;
  const int n   = idx / 16;
  const int y = pos / 4, xx = pos % 4;
  const float* t2 = ws + F_T2 + (size_t)n * 1440;
  float ss = 0.f;
  for (int c = 0; c < 40; ++c)
    for (int i = 0; i < 3; ++i)
      for (int j = 0; j < 3; ++j) {
        const float v = t2[c*36 + (y+i)*6 + xx + j];
        ss = __fadd_rn(ss, __fmul_rn(v, v));
      }
  ws[F_XN3 + idx] = __fadd_rn(__fsqrt_rn(__fadd_rn(ss, 1e-12f)), ws[F_QV+3]);
}

// ---- layer3 scs: store y values (pre-pow) ----
__global__ __launch_bounds__(256) void k3_scs(float* __restrict__ ws)
{
  const int idx = blockIdx.x * 256 + threadIdx.x;
  if (idx >= 1024*40*16) return;
  const int pos = idx % 16;
  const int o   = (idx / 16) % 40;
  const int n   = idx / (40*16);
  const int y = pos / 4, xx = pos % 4;
  const float* t2 = ws + F_T2 + (size_t)n * 1440;
  const float* wn = ws + F_WN3 + o*360;
  float num = 0.f;
  for (int c = 0; c < 40; ++c)
    for (int i = 0; i < 3; ++i)
      for (int j = 0; j < 3; ++j)
        num = __fadd_rn(num, __fmul_rn(t2[c*36 + (y+i)*6 + xx + j], wn[c*9 + i*3 + j]));
  ws[F_A3 + idx] = __fdiv_rn(num, ws[F_XN3 + (size_t)n*16 + pos]);
}

// ---- layer3 pool 4x4 over y, 2 exact pows ----
__global__ __launch_bounds__(256) void k3_pool(float* __restrict__ ws)
{
  const int idx = blockIdx.x * 256 + threadIdx.x;
  if (idx >= 1024*40) return;
  const int o = idx % 40;
  const float* a = ws + F_A3 + (size_t)idx * 16;
  float ymax = a[0], ymin = a[0];
  for (int k = 1; k < 16; ++k) {
    ymax = fmaxf(ymax, a[k]);
    ymin = fminf(ymin, a[k]);
  }
  const float e  = ws[F_EXPO3 + o];
  const float fp = scs_pow_f(ymax, e);
  const float fn = scs_pow_f(ymin, e);
  ws[F_VAL + idx] = (fp >= -fn) ? fp : fn;
}

// ---- head ----
__global__ __launch_bounds__(256) void k_head(
    const float* __restrict__ ws, const float* __restrict__ wo,
    const float* __restrict__ bo, float* __restrict__ out)
{
  const int idx = blockIdx.x * 256 + threadIdx.x;
  if (idx >= 1024*10) return;
  const int k = idx % 10;
  const int n = idx / 10;
  const float* v = ws + F_VAL + (size_t)n * 40;
  float s = 0.f;
  for (int c = 0; c < 40; ++c) s = __fadd_rn(s, __fmul_rn(v[c], wo[k*40 + c]));
  s = __fadd_rn(s, bo[k]);
  out[(size_t)n * 10 + k] = s;
}

extern "C" void kernel_launch(void* const* d_in, const int* in_sizes, int n_in,
                              void* d_out, int out_size, void* d_ws, size_t ws_size,
                              hipStream_t stream) {
  (void)in_sizes; (void)n_in; (void)out_size; (void)ws_size;
  const float* x   = (const float*)d_in[0];
  const float* w1  = (const float*)d_in[1];
  const float* p1  = (const float*)d_in[2];
  const float* q1  = (const float*)d_in[3];
  const float* w2d = (const float*)d_in[4];
  const float* p2d = (const float*)d_in[5];
  const float* q2d = (const float*)d_in[6];
  const float* w2p = (const float*)d_in[7];
  const float* p2p = (const float*)d_in[8];
  const float* q2p = (const float*)d_in[9];
  const float* w3  = (const float*)d_in[10];
  const float* p3  = (const float*)d_in[11];
  const float* q3  = (const float*)d_in[12];
  const float* wo  = (const float*)d_in[13];
  const float* bo  = (const float*)d_in[14];
  float* ws  = (float*)d_ws;
  float* out = (float*)d_out;

  hipLaunchKernelGGL(k_prep, dim3(1), dim3(256), 0, stream,
                     w1, p1, q1, w2d, p2d, q2d, w2p, p2p, q2p, w3, p3, q3, ws);
  hipLaunchKernelGGL(k1_norm,     dim3((1024*784    +255)/256), dim3(256), 0, stream, x, ws);
  hipLaunchKernelGGL(k1_scs_pool, dim3((1024*80*196 +255)/256), dim3(256), 0, stream, x, ws);
  hipLaunchKernelGGL(k2_dw,       dim3((1024*80*144 +255)/256), dim3(256), 0, stream, ws);
  hipLaunchKernelGGL(k2_norm,     dim3((1024*144    +255)/256), dim3(256), 0, stream, ws);
  hipLaunchKernelGGL(k2_pw_pool,  dim3((1024*40*36  +255)/256), dim3(256), 0, stream, ws);
  hipLaunchKernelGGL(k3_norm,     dim3((1024*16     +255)/256), dim3(256), 0, stream, ws);
  hipLaunchKernelGGL(k3_scs,      dim3((1024*40*16  +255)/256), dim3(256), 0, stream, ws);
  hipLaunchKernelGGL(k3_pool,     dim3((1024*40     +255)/256), dim3(256), 0, stream, ws);
  hipLaunchKernelGGL(k_head,      dim3((1024*10     +255)/256), dim3(256), 0, stream, ws, wo, bo, out);
}